// Round 1
// baseline (68.585 us; speedup 1.0000x reference)
//
#include <hip/hip_runtime.h>
#include <hip/hip_bf16.h>

#define DN 128
#define DE 64
#define NN 512

typedef __bf16 bf16x8 __attribute__((ext_vector_type(8)));
typedef float  f32x4  __attribute__((ext_vector_type(4)));

// -------- prep 1: rms_norm(nodes)*g_node, then rp = nn@Wr + b, cp = nn@Wc ----
// grid: B*N (=1024) blocks of 64 threads (one wave per node row)
__global__ void prep_nodes(const float* __restrict__ nodes,
                           const float* __restrict__ g_node,
                           const float* __restrict__ W,
                           const float* __restrict__ bias,
                           float* __restrict__ rp, float* __restrict__ cp) {
    const int row = blockIdx.x;      // b*N + i
    const int l   = threadIdx.x;     // 0..63
    __shared__ float nn[DN];

    float x0 = nodes[row * DN + l];
    float x1 = nodes[row * DN + l + 64];
    float ssq = x0 * x0 + x1 * x1;
    #pragma unroll
    for (int m = 1; m < 64; m <<= 1) ssq += __shfl_xor(ssq, m, 64);
    float scale = rsqrtf(ssq * (1.0f / DN) + 1.1920929e-7f);
    nn[l]      = x0 * scale * g_node[l];
    nn[l + 64] = x1 * scale * g_node[l + 64];
    __syncthreads();

    float accr = bias[l];
    float accc = 0.0f;
    #pragma unroll 4
    for (int d = 0; d < DN; ++d) {
        float nd = nn[d];
        accr += nd * W[d * DE + l];          // Wr = W[0:128]
        accc += nd * W[(DN + d) * DE + l];   // Wc = W[128:256]
    }
    rp[row * DE + l] = accr;
    cp[row * DE + l] = accc;
}

// -------- prep 2: pack g_edge[k]*We[k][col] into bf16 MFMA B-fragment order --
// frag f = kh*4 + ct (kh: K-half 0..1, ct: col-tile 0..3)
// lane l, elem e: k = kh*32 + (l>>4)*8 + e ; col = ct*16 + (l&15)
__global__ void prep_weg(const float* __restrict__ W,
                         const float* __restrict__ g_edge,
                         __bf16* __restrict__ weg) {
    const int l = threadIdx.x;  // 0..63
    for (int kh = 0; kh < 2; ++kh)
        for (int ct = 0; ct < 4; ++ct) {
            const int f = kh * 4 + ct;
            #pragma unroll
            for (int e = 0; e < 8; ++e) {
                const int k   = kh * 32 + (l >> 4) * 8 + e;
                const int col = ct * 16 + (l & 15);
                weg[(f * 64 + l) * 8 + e] =
                    (__bf16)(g_edge[k] * W[(2 * DN + k) * DE + col]);
            }
        }
}

// -------- main: per edge, rms_norm + @WeG (MFMA) + rp + cp ------------------
// block = 256 (4 waves); each wave: 4 M-tiles of 16 edges along j.
// block covers (b,i)=bid>>1, j in [ (bid&1)*256, +256 )
__global__ __launch_bounds__(256) void main_kernel(
    const float* __restrict__ edges, const float* __restrict__ rp,
    const float* __restrict__ cp, const __bf16* __restrict__ weg,
    float* __restrict__ out) {
    const int bid  = blockIdx.x;       // 0..2047
    const int row  = bid >> 1;         // b*N + i
    const int jblk = bid & 1;
    const int w    = threadIdx.x >> 6;
    const int l    = threadIdx.x & 63;
    const int jw   = jblk * 256 + w * 64;   // wave's j base; tiles at jw + t*16

    // whole (g_edge-scaled) We in registers: 8 frags x 4 VGPR
    bf16x8 wf[8];
    #pragma unroll
    for (int f = 0; f < 8; ++f)
        wf[f] = *reinterpret_cast<const bf16x8*>(weg + (f * 64 + l) * 8);

    const int r16 = l & 15;   // A row within tile / D col
    const int kg  = l >> 4;   // k-group / D row-group
    float rpv[4];
    #pragma unroll
    for (int c = 0; c < 4; ++c) rpv[c] = rp[row * DE + c * 16 + r16];

    const int bN = (row / NN) * NN;   // b*512 (base row of cp)

    for (int t = 0; t < 4; ++t) {
        const int jt = jw + t * 16;
        const float* ep = edges + ((size_t)row * NN + jt + r16) * DE + kg * 8;
        f32x4 x0a = *reinterpret_cast<const f32x4*>(ep);
        f32x4 x0b = *reinterpret_cast<const f32x4*>(ep + 4);
        f32x4 x1a = *reinterpret_cast<const f32x4*>(ep + 32);
        f32x4 x1b = *reinterpret_cast<const f32x4*>(ep + 36);

        float ssq = 0.0f;
        #pragma unroll
        for (int e = 0; e < 4; ++e)
            ssq += x0a[e] * x0a[e] + x0b[e] * x0b[e]
                 + x1a[e] * x1a[e] + x1b[e] * x1b[e];
        ssq += __shfl_xor(ssq, 16, 64);
        ssq += __shfl_xor(ssq, 32, 64);
        const float scale = rsqrtf(ssq * (1.0f / DE) + 1.1920929e-7f);

        // raw x -> bf16 fragments (rms scale folded into epilogue)
        bf16x8 a0, a1;
        #pragma unroll
        for (int e = 0; e < 4; ++e) {
            a0[e]     = (__bf16)x0a[e];
            a0[e + 4] = (__bf16)x0b[e];
            a1[e]     = (__bf16)x1a[e];
            a1[e + 4] = (__bf16)x1b[e];
        }

        f32x4 acc[4];
        #pragma unroll
        for (int c = 0; c < 4; ++c) {
            f32x4 z = {0.f, 0.f, 0.f, 0.f};
            z = __builtin_amdgcn_mfma_f32_16x16x32_bf16(a0, wf[c],     z, 0, 0, 0);
            z = __builtin_amdgcn_mfma_f32_16x16x32_bf16(a1, wf[4 + c], z, 0, 0, 0);
            acc[c] = z;
        }

        // scales for the 4 D-rows this lane owns (row = kg*4 + r, held by lane kg*4+r)
        float sc[4];
        #pragma unroll
        for (int r = 0; r < 4; ++r) sc[r] = __shfl(scale, kg * 4 + r, 64);

        #pragma unroll
        for (int r = 0; r < 4; ++r) {
            const int j = jt + kg * 4 + r;
            const float* cprow = cp + (size_t)(bN + j) * DE;
            float* orow = out + ((size_t)row * NN + j) * DE;
            #pragma unroll
            for (int c = 0; c < 4; ++c) {
                const int col = c * 16 + r16;
                orow[col] = acc[c][r] * sc[r] + rpv[c] + cprow[col];
            }
        }
    }
}

extern "C" void kernel_launch(void* const* d_in, const int* in_sizes, int n_in,
                              void* d_out, int out_size, void* d_ws, size_t ws_size,
                              hipStream_t stream) {
    const float* edges  = (const float*)d_in[0];
    const float* nodes  = (const float*)d_in[1];
    const float* g_node = (const float*)d_in[2];
    const float* g_edge = (const float*)d_in[3];
    const float* W      = (const float*)d_in[4];
    const float* bias   = (const float*)d_in[5];
    float* out = (float*)d_out;

    float*  rp  = (float*)d_ws;                 // 1024*64 f32 = 256 KB
    float*  cp  = rp + 1024 * DE;               // 256 KB
    __bf16* weg = (__bf16*)(cp + 1024 * DE);    // 8*64*8 bf16 = 8 KB

    prep_nodes<<<dim3(1024), dim3(64), 0, stream>>>(nodes, g_node, W, bias, rp, cp);
    prep_weg<<<dim3(1), dim3(64), 0, stream>>>(W, g_edge, weg);
    main_kernel<<<dim3(2048), dim3(256), 0, stream>>>(edges, rp, cp, weg, out);
}